// Round 1
// baseline (160.327 us; speedup 1.0000x reference)
//
#include <hip/hip_runtime.h>

#define NN 4096
#define C 256
#define NH 4
#define CH 64
#define JSPLIT 8
#define JSLICE (NN / JSPLIT)     // 512
#define NJT (JSLICE / 32)        // 16

typedef float f32x4 __attribute__((ext_vector_type(4)));
typedef __bf16 b16x8 __attribute__((ext_vector_type(8)));
typedef unsigned short u16x8 __attribute__((ext_vector_type(8)));
typedef unsigned int u32x4 __attribute__((ext_vector_type(4)));

__device__ inline float fast_exp2(float x) {
#if __has_builtin(__builtin_amdgcn_exp2f)
  return __builtin_amdgcn_exp2f(x);
#else
  return exp2f(x);
#endif
}

// pack two f32 -> (bf16(f0) | bf16(f1)<<16), round-half-up via +0x8000, v_perm pack
__device__ inline unsigned pack2bf(float f0, float f1) {
  unsigned u0 = __float_as_uint(f0) + 0x8000u;
  unsigned u1 = __float_as_uint(f1) + 0x8000u;
  return __builtin_amdgcn_perm(u1, u0, 0x07060302u);
}

// ---------------- Kernel 0: prep — X->bf16, W->bf16 transposed (adj packing REMOVED:
// adj is now consumed directly by k_attn; each element is read exactly once anyway)
__global__ __launch_bounds__(256) void k_prep(
    const float* __restrict__ X, const float* __restrict__ W,
    unsigned short* __restrict__ Xbf, unsigned short* __restrict__ WT) {
  const int b = blockIdx.x, t = threadIdx.x;
  if (b < 1024) {
    const int idx = b * 256 + t;
    const float4 v = ((const float4*)X)[idx];
    uint2 st;
    st.x = pack2bf(v.x, v.y);
    st.y = pack2bf(v.z, v.w);
    ((uint2*)Xbf)[idx] = st;
  } else {
    const int c = b - 1024;
    const float w = W[(size_t)t * C + c];
    WT[(size_t)c * C + t] = (unsigned short)((__float_as_uint(w) + 0x8000u) >> 16);
  }
}

// ---------------- Kernel 1: feats = X@W + b via MFMA; epilogue stores
// B-fragment-major tiles F[jt][h][g][lane]*8bf16; per-(h,j) exp pairs EdT2={e^d, e^{.2d}};
// per-(row,h) softmax-stable scale pairs srcAB={exp2(s*L2E-m2), exp2(.2s*L2E-m2)}.
__global__ __launch_bounds__(256) void k_feats(
    const unsigned short* __restrict__ Xbf, const unsigned short* __restrict__ WT,
    const float* __restrict__ bias, const float* __restrict__ av,
    unsigned short* __restrict__ F, float2* __restrict__ srcAB,
    float2* __restrict__ EdT2) {
  const int i0 = blockIdx.x * 16;
  const int h = threadIdx.x >> 6;
  const int lane = threadIdx.x & 63;
  const int q = lane >> 4, n = lane & 15;
  const int c0 = h * CH;
  const float LOG2E = 1.4426950408889634f;

  const f32x4 zero = {0.f, 0.f, 0.f, 0.f};
  f32x4 acc[4];
#pragma unroll
  for (int g = 0; g < 4; ++g) acc[g] = zero;

  const unsigned short* ap = Xbf + (size_t)(i0 + n) * C + q * 8;
#pragma unroll
  for (int kt = 0; kt < 8; ++kt) {
    const b16x8 aF = __builtin_bit_cast(b16x8, *(const u16x8*)(ap + kt * 32));
#pragma unroll
    for (int g = 0; g < 4; ++g) {
      const b16x8 bF = __builtin_bit_cast(b16x8,
          *(const u16x8*)(WT + (size_t)(c0 + g * 16 + n) * C + kt * 32 + q * 8));
      acc[g] = __builtin_amdgcn_mfma_f32_16x16x32_bf16(aF, bF, acc[g], 0, 0, 0);
    }
  }

  float fb[4][4], asv[4], adv[4];
#pragma unroll
  for (int g = 0; g < 4; ++g) {
    const float bs = bias[c0 + g * 16 + n];
    asv[g] = av[h * 128 + g * 16 + n];
    adv[g] = av[h * 128 + 64 + g * 16 + n];
#pragma unroll
    for (int r = 0; r < 4; ++r) fb[g][r] = acc[g][r] + bs;
  }
  // fragment-major store: tile (jt = i0>>5, h, g); j-in-tile = 16*half+4q+r
  const int jt = i0 >> 5, half = (i0 >> 4) & 1;
  const int qp = half * 2 + (q >> 1);          // q' in B-fragment
#pragma unroll
  for (int g = 0; g < 4; ++g) {
    uint2 st;
    st.x = pack2bf(fb[g][0], fb[g][1]);
    st.y = pack2bf(fb[g][2], fb[g][3]);
    *(uint2*)(F + ((size_t)((jt * NH + h) * 4 + g)) * 512 + (qp * 16 + n) * 8 + 4 * (q & 1)) = st;
  }
  // src/dst epilogue: factor the softmax exp.
  //   e_ij = exp2(L2E*leaky(s_i + d_j) - m2_i)
  //        = max( e^{d_j} * exp2(L2E*s_i - m2_i), e^{.2 d_j} * exp2(.2 L2E*s_i - m2_i) )
  // so per-j exps and per-row scales are precomputed here; k_attn has NO transcendentals.
#pragma unroll
  for (int r = 0; r < 4; ++r) {
    float p = 0.f, d = 0.f;
#pragma unroll
    for (int g = 0; g < 4; ++g) {
      p = fmaf(fb[g][r], asv[g], p);
      d = fmaf(fb[g][r], adv[g], d);
    }
#pragma unroll
    for (int m = 1; m < 16; m <<= 1) {
      p += __shfl_xor(p, m);
      d += __shfl_xor(d, m);
    }
    if (n == 0) {
      const int row = i0 + q * 4 + r;
      const float dL = d * LOG2E;
      EdT2[(size_t)h * NN + row] = make_float2(fast_exp2(dL), fast_exp2(0.2f * dL));
      const float x = p + 16.0f;
      const float m2 = fmaxf(x, 0.2f * x) * LOG2E;   // = L2E * leaky(s+16) >= L2E*leaky(s+d)
      srcAB[(size_t)row * NH + h] = make_float2(
          fast_exp2(fmaf(p, LOG2E, -m2)),
          fast_exp2(fmaf(0.2f * p, LOG2E, -m2)));
    }
  }
}

// ---------------- Kernel 2: masked-softmax attention + PV via MFMA
// wave = 32 rows x 1 head; adj read DIRECTLY (each element consumed exactly once);
// inner loop is mul/max/select only — zero transcendentals.
__global__ __launch_bounds__(256, 4) void k_attn(
    const int* __restrict__ adj,
    const unsigned short* __restrict__ F,
    const float2* __restrict__ srcAB, const float2* __restrict__ EdT2,
    _Float16* __restrict__ pacc, float* __restrict__ lpart) {
  const int slice = blockIdx.x;
  const int i0 = blockIdx.y * 32;
  const int h = threadIdx.x >> 6;
  const int lane = threadIdx.x & 63;
  const int q = lane >> 4, n = lane & 15;
  const int jbase = slice * JSLICE;

  const int r0 = i0 + n, r1 = i0 + 16 + n;
  const float2 ab0 = srcAB[(size_t)r0 * NH + h];
  const float2 ab1 = srcAB[(size_t)r1 * NH + h];

  const f32x4 zero = {0.f, 0.f, 0.f, 0.f};
  f32x4 acc0[4], acc1[4], lacc0 = zero, lacc1 = zero;
#pragma unroll
  for (int g = 0; g < 4; ++g) { acc0[g] = zero; acc1[g] = zero; }

  u16x8 ou;
#pragma unroll
  for (int jj = 0; jj < 8; ++jj) ou[jj] = 0x3F80;
  const b16x8 ones = __builtin_bit_cast(b16x8, ou);

  // lane (q,n) owns j = jt*32 + q*8 .. +7 for rows r0/r1 (A-fragment layout)
  const int* aj0 = adj + (size_t)r0 * NN + jbase + q * 8;
  const int* aj1 = adj + (size_t)r1 * NN + jbase + q * 8;
  const float* dp2 = (const float*)(EdT2 + (size_t)h * NN + jbase);
  const unsigned short* fp = F + ((size_t)((jbase >> 5) * NH + h) * 4) * 512 + lane * 8;

#pragma unroll
  for (int a = 0; a < 4; ++a) {
#pragma unroll
    for (int b = 0; b < 4; ++b) {
      const int jt = a * 4 + b;
      // coalesced B-fragment loads: 4 x 1KB sequential
      b16x8 bF[4];
#pragma unroll
      for (int g = 0; g < 4; ++g)
        bF[g] = __builtin_bit_cast(b16x8,
            *(const u16x8*)(fp + (size_t)(jt * NH * 4 + g) * 512));

      // adjacency for this lane's 8 j's, both rows: 4 x dwordx4
      const int4 M0a = *(const int4*)(aj0 + jt * 32);
      const int4 M0b = *(const int4*)(aj0 + jt * 32 + 4);
      const int4 M1a = *(const int4*)(aj1 + jt * 32);
      const int4 M1b = *(const int4*)(aj1 + jt * 32 + 4);
      const int m0[8] = {M0a.x, M0a.y, M0a.z, M0a.w, M0b.x, M0b.y, M0b.z, M0b.w};
      const int m1[8] = {M1a.x, M1a.y, M1a.z, M1a.w, M1b.x, M1b.y, M1b.z, M1b.w};

      // exp pairs {e^d, e^{.2d}} for this lane's 8 j's (broadcast loads)
      const float* dq = dp2 + jt * 64 + q * 16;
      const float4 dd0 = *(const float4*)(dq);
      const float4 dd1 = *(const float4*)(dq + 4);
      const float4 dd2 = *(const float4*)(dq + 8);
      const float4 dd3 = *(const float4*)(dq + 12);
      const float4 dd[4] = {dd0, dd1, dd2, dd3};

      u32x4 pk0, pk1;
#pragma unroll
      for (int k = 0; k < 4; ++k) {
        const float4 d = dd[k];
        const float e00 = m0[2 * k]     ? fmaxf(d.x * ab0.x, d.y * ab0.y) : 0.f;
        const float e01 = m0[2 * k + 1] ? fmaxf(d.z * ab0.x, d.w * ab0.y) : 0.f;
        const float e10 = m1[2 * k]     ? fmaxf(d.x * ab1.x, d.y * ab1.y) : 0.f;
        const float e11 = m1[2 * k + 1] ? fmaxf(d.z * ab1.x, d.w * ab1.y) : 0.f;
        pk0[k] = pack2bf(e00, e01);
        pk1[k] = pack2bf(e10, e11);
      }
      const b16x8 E0 = __builtin_bit_cast(b16x8, pk0);
      const b16x8 E1 = __builtin_bit_cast(b16x8, pk1);
#pragma unroll
      for (int g = 0; g < 4; ++g) {
        acc0[g] = __builtin_amdgcn_mfma_f32_16x16x32_bf16(E0, bF[g], acc0[g], 0, 0, 0);
        acc1[g] = __builtin_amdgcn_mfma_f32_16x16x32_bf16(E1, bF[g], acc1[g], 0, 0, 0);
      }
      lacc0 = __builtin_amdgcn_mfma_f32_16x16x32_bf16(E0, ones, lacc0, 0, 0, 0);
      lacc1 = __builtin_amdgcn_mfma_f32_16x16x32_bf16(E1, ones, lacc1, 0, 0, 0);
    }
  }

#pragma unroll
  for (int g = 0; g < 4; ++g)
#pragma unroll
    for (int r = 0; r < 4; ++r) {
      const int col = h * CH + g * 16 + n;
      pacc[((size_t)slice * NN + i0 + q * 4 + r) * C + col] = (_Float16)acc0[g][r];
      pacc[((size_t)slice * NN + i0 + 16 + q * 4 + r) * C + col] = (_Float16)acc1[g][r];
    }
  if (n == 0) {
#pragma unroll
    for (int r = 0; r < 4; ++r) {
      lpart[((size_t)slice * NN + i0 + q * 4 + r) * NH + h] = lacc0[r];
      lpart[((size_t)slice * NN + i0 + 16 + q * 4 + r) * NH + h] = lacc1[r];
    }
  }
}

// ---------------- Kernel 3: combine j-slices, divide
__global__ __launch_bounds__(256) void k_final(
    const _Float16* __restrict__ pacc, const float* __restrict__ lpart,
    float* __restrict__ out) {
  const int i = blockIdx.x;
  const int c = threadIdx.x;
  const int h = c >> 6;
  float l = 0.f, sa = 0.f;
#pragma unroll
  for (int sp = 0; sp < JSPLIT; ++sp) {
    l += lpart[((size_t)sp * NN + i) * NH + h];
    sa += (float)pacc[((size_t)sp * NN + i) * C + c];
  }
  out[(size_t)i * C + c] = sa / l;
}

extern "C" void kernel_launch(void* const* d_in, const int* in_sizes, int n_in,
                              void* d_out, int out_size, void* d_ws, size_t ws_size,
                              hipStream_t stream) {
  const float* nf   = (const float*)d_in[0];
  const int* adj    = (const int*)d_in[1];
  const float* W    = (const float*)d_in[2];
  const float* bias = (const float*)d_in[3];
  const float* av   = (const float*)d_in[4];
  float* out = (float*)d_out;

  char* ws = (char*)d_ws;
  unsigned short* Xbf = (unsigned short*)ws;                                // 2 MB
  unsigned short* WT  = (unsigned short*)(ws + (2u << 20));                 // 128 KB
  unsigned short* F   = (unsigned short*)(ws + (2u << 20) + (128u << 10));  // 2 MB
  float2* srcAB = (float2*)(ws + (4u << 20) + (128u << 10));                // 128 KB
  float2* EdT2  = (float2*)(ws + (4u << 20) + (256u << 10));                // 128 KB
  float* lpart  = (float*)(ws + (4u << 20) + (384u << 10));                 // 512 KB
  _Float16* pacc = (_Float16*)(ws + (8u << 20));                            // 16 MB

  k_prep<<<1280, 256, 0, stream>>>(nf, W, Xbf, WT);
  k_feats<<<NN / 16, 256, 0, stream>>>(Xbf, WT, bias, av, F, srcAB, EdT2);
  dim3 g2(JSPLIT, NN / 32);
  k_attn<<<g2, 256, 0, stream>>>(adj, F, srcAB, EdT2, pacc, lpart);
  k_final<<<NN, 256, 0, stream>>>(pacc, lpart, out);
}

// Round 2
// 145.660 us; speedup vs baseline: 1.1007x; 1.1007x over previous
//
#include <hip/hip_runtime.h>

#define NN 4096
#define C 256
#define NH 4
#define CH 64
#define JSPLIT 16
#define JSLICE (NN / JSPLIT)     // 256
#define NJT (JSLICE / 32)        // 8

typedef float f32x4 __attribute__((ext_vector_type(4)));
typedef __bf16 b16x8 __attribute__((ext_vector_type(8)));
typedef unsigned short u16x8 __attribute__((ext_vector_type(8)));
typedef unsigned int u32x4 __attribute__((ext_vector_type(4)));

__device__ inline float fast_exp2(float x) {
#if __has_builtin(__builtin_amdgcn_exp2f)
  return __builtin_amdgcn_exp2f(x);
#else
  return exp2f(x);
#endif
}

// pack two f32 -> (bf16(f0) | bf16(f1)<<16), round-half-up via +0x8000, v_perm pack
__device__ inline unsigned pack2bf(float f0, float f1) {
  unsigned u0 = __float_as_uint(f0) + 0x8000u;
  unsigned u1 = __float_as_uint(f1) + 0x8000u;
  return __builtin_amdgcn_perm(u1, u0, 0x07060302u);
}

// ---------------- Kernel 0: prep — pack adj to bits (streaming, hides the 64MB read
// in a BW-bound kernel), X->bf16, W->bf16 transposed
__global__ __launch_bounds__(256) void k_prep(
    const int* __restrict__ adj, const float* __restrict__ X,
    const float* __restrict__ W, unsigned char* __restrict__ packed,
    unsigned short* __restrict__ Xbf, unsigned short* __restrict__ WT) {
  const int b = blockIdx.x, t = threadIdx.x;
  if (b < 8192) {
    const int idx = b * 256 + t;
    const int4 a0 = *(const int4*)(adj + (size_t)idx * 8);
    const int4 a1 = *(const int4*)(adj + (size_t)idx * 8 + 4);
    unsigned m = 0;
    m |= (a0.x != 0) ? 1u : 0u;   m |= (a0.y != 0) ? 2u : 0u;
    m |= (a0.z != 0) ? 4u : 0u;   m |= (a0.w != 0) ? 8u : 0u;
    m |= (a1.x != 0) ? 16u : 0u;  m |= (a1.y != 0) ? 32u : 0u;
    m |= (a1.z != 0) ? 64u : 0u;  m |= (a1.w != 0) ? 128u : 0u;
    packed[idx] = (unsigned char)m;
  } else if (b < 9216) {
    const int idx = (b - 8192) * 256 + t;
    const float4 v = ((const float4*)X)[idx];
    uint2 st;
    st.x = pack2bf(v.x, v.y);
    st.y = pack2bf(v.z, v.w);
    ((uint2*)Xbf)[idx] = st;
  } else {
    const int c = b - 9216;
    const float w = W[(size_t)t * C + c];
    WT[(size_t)c * C + t] = (unsigned short)((__float_as_uint(w) + 0x8000u) >> 16);
  }
}

// ---------------- Kernel 1: feats = X@W + b via MFMA; epilogue stores
// B-fragment-major tiles F[jt][h][g][lane]*8bf16; per-(h,j) exp pairs EdT2={e^d, e^{.2d}};
// per-(row,h) softmax-stable scale pairs srcAB={exp2(s*L2E-m2), exp2(.2s*L2E-m2)}.
__global__ __launch_bounds__(256) void k_feats(
    const unsigned short* __restrict__ Xbf, const unsigned short* __restrict__ WT,
    const float* __restrict__ bias, const float* __restrict__ av,
    unsigned short* __restrict__ F, float2* __restrict__ srcAB,
    float2* __restrict__ EdT2) {
  const int i0 = blockIdx.x * 16;
  const int h = threadIdx.x >> 6;
  const int lane = threadIdx.x & 63;
  const int q = lane >> 4, n = lane & 15;
  const int c0 = h * CH;
  const float LOG2E = 1.4426950408889634f;

  const f32x4 zero = {0.f, 0.f, 0.f, 0.f};
  f32x4 acc[4];
#pragma unroll
  for (int g = 0; g < 4; ++g) acc[g] = zero;

  const unsigned short* ap = Xbf + (size_t)(i0 + n) * C + q * 8;
#pragma unroll
  for (int kt = 0; kt < 8; ++kt) {
    const b16x8 aF = __builtin_bit_cast(b16x8, *(const u16x8*)(ap + kt * 32));
#pragma unroll
    for (int g = 0; g < 4; ++g) {
      const b16x8 bF = __builtin_bit_cast(b16x8,
          *(const u16x8*)(WT + (size_t)(c0 + g * 16 + n) * C + kt * 32 + q * 8));
      acc[g] = __builtin_amdgcn_mfma_f32_16x16x32_bf16(aF, bF, acc[g], 0, 0, 0);
    }
  }

  float fb[4][4], asv[4], adv[4];
#pragma unroll
  for (int g = 0; g < 4; ++g) {
    const float bs = bias[c0 + g * 16 + n];
    asv[g] = av[h * 128 + g * 16 + n];
    adv[g] = av[h * 128 + 64 + g * 16 + n];
#pragma unroll
    for (int r = 0; r < 4; ++r) fb[g][r] = acc[g][r] + bs;
  }
  // fragment-major store: tile (jt = i0>>5, h, g); j-in-tile = 16*half+4q+r
  const int jt = i0 >> 5, half = (i0 >> 4) & 1;
  const int qp = half * 2 + (q >> 1);          // q' in B-fragment
#pragma unroll
  for (int g = 0; g < 4; ++g) {
    uint2 st;
    st.x = pack2bf(fb[g][0], fb[g][1]);
    st.y = pack2bf(fb[g][2], fb[g][3]);
    *(uint2*)(F + ((size_t)((jt * NH + h) * 4 + g)) * 512 + (qp * 16 + n) * 8 + 4 * (q & 1)) = st;
  }
  // src/dst epilogue: factor the softmax exp.
  //   e_ij = exp2(L2E*leaky(s_i + d_j) - m2_i)
  //        = max( e^{d_j} * exp2(L2E*s_i - m2_i), e^{.2 d_j} * exp2(.2 L2E*s_i - m2_i) )
  // so per-j exps and per-row scales are precomputed here; k_attn has NO transcendentals.
#pragma unroll
  for (int r = 0; r < 4; ++r) {
    float p = 0.f, d = 0.f;
#pragma unroll
    for (int g = 0; g < 4; ++g) {
      p = fmaf(fb[g][r], asv[g], p);
      d = fmaf(fb[g][r], adv[g], d);
    }
#pragma unroll
    for (int m = 1; m < 16; m <<= 1) {
      p += __shfl_xor(p, m);
      d += __shfl_xor(d, m);
    }
    if (n == 0) {
      const int row = i0 + q * 4 + r;
      const float dL = d * LOG2E;
      EdT2[(size_t)h * NN + row] = make_float2(fast_exp2(dL), fast_exp2(0.2f * dL));
      const float x = p + 16.0f;
      const float m2 = fmaxf(x, 0.2f * x) * LOG2E;   // = L2E * leaky(s+16) >= L2E*leaky(s+d)
      srcAB[(size_t)row * NH + h] = make_float2(
          fast_exp2(fmaf(p, LOG2E, -m2)),
          fast_exp2(fmaf(0.2f * p, LOG2E, -m2)));
    }
  }
}

// ---------------- Kernel 2: masked-softmax attention + PV via MFMA
// wave = 32 rows x 1 head; packed masks preloaded + shfl-redistributed;
// inner loop is mul/max/select only — zero transcendentals.
// JSPLIT=16 -> 2048 blocks -> 8 blocks/CU at VGPR<=64 (latency hiding).
__global__ __launch_bounds__(256, 4) void k_attn(
    const unsigned char* __restrict__ packed,
    const unsigned short* __restrict__ F,
    const float2* __restrict__ srcAB, const float2* __restrict__ EdT2,
    _Float16* __restrict__ pacc, float* __restrict__ lpart) {
  const int slice = blockIdx.x;
  const int i0 = blockIdx.y * 32;
  const int h = threadIdx.x >> 6;
  const int lane = threadIdx.x & 63;
  const int q = lane >> 4, n = lane & 15;
  const int jbase = slice * JSLICE;

  const int r0 = i0 + n, r1 = i0 + 16 + n;
  const float2 ab0 = srcAB[(size_t)r0 * NH + h];
  const float2 ab1 = srcAB[(size_t)r1 * NH + h];

  const f32x4 zero = {0.f, 0.f, 0.f, 0.f};
  f32x4 acc0[4], acc1[4], lacc0 = zero, lacc1 = zero;
#pragma unroll
  for (int g = 0; g < 4; ++g) { acc0[g] = zero; acc1[g] = zero; }

  u16x8 ou;
#pragma unroll
  for (int jj = 0; jj < 8; ++jj) ou[jj] = 0x3F80;
  const b16x8 ones = __builtin_bit_cast(b16x8, ou);

  // preload slice masks: lane (q,n) holds 8-byte chunk q of rows r0 / r1 (32B/row-slice)
  const uint2 m20 = *(const uint2*)(packed + (size_t)r0 * 512 + (jbase >> 3) + q * 8);
  const uint2 m21 = *(const uint2*)(packed + (size_t)r1 * 512 + (jbase >> 3) + q * 8);

  const float* dp2 = (const float*)(EdT2 + (size_t)h * NN + jbase);
  const unsigned short* fp = F + ((size_t)((jbase >> 5) * NH + h) * 4) * 512 + lane * 8;

#pragma unroll
  for (int a = 0; a < 4; ++a) {
#pragma unroll
    for (int b = 0; b < 2; ++b) {
      const int jt = a * 2 + b;
      // coalesced B-fragment loads: 4 x 1KB sequential
      b16x8 bF[4];
#pragma unroll
      for (int g = 0; g < 4; ++g)
        bF[g] = __builtin_bit_cast(b16x8,
            *(const u16x8*)(fp + (size_t)(jt * NH * 4 + g) * 512));

      // masks via shfl from preloaded chunks: byte (a*8 + b*4 + q), src lane a*16+n
      const int w0 = b ? (int)m20.y : (int)m20.x;
      const int w1 = b ? (int)m21.y : (int)m21.x;
      const unsigned Mb0 = (unsigned(__shfl(w0, a * 16 + n)) >> (q * 8)) & 0xffu;
      const unsigned Mb1 = (unsigned(__shfl(w1, a * 16 + n)) >> (q * 8)) & 0xffu;

      // exp pairs {e^d, e^{.2d}} for this lane's 8 j's (broadcast loads)
      const float* dq = dp2 + jt * 64 + q * 16;
      const float4 dd0 = *(const float4*)(dq);
      const float4 dd1 = *(const float4*)(dq + 4);
      const float4 dd2 = *(const float4*)(dq + 8);
      const float4 dd3 = *(const float4*)(dq + 12);
      const float4 dd[4] = {dd0, dd1, dd2, dd3};

      u32x4 pk0, pk1;
#pragma unroll
      for (int k = 0; k < 4; ++k) {
        const float4 d = dd[k];
        const float e00 = (Mb0 & (1u << (2 * k))) ? fmaxf(d.x * ab0.x, d.y * ab0.y) : 0.f;
        const float e01 = (Mb0 & (2u << (2 * k))) ? fmaxf(d.z * ab0.x, d.w * ab0.y) : 0.f;
        const float e10 = (Mb1 & (1u << (2 * k))) ? fmaxf(d.x * ab1.x, d.y * ab1.y) : 0.f;
        const float e11 = (Mb1 & (2u << (2 * k))) ? fmaxf(d.z * ab1.x, d.w * ab1.y) : 0.f;
        pk0[k] = pack2bf(e00, e01);
        pk1[k] = pack2bf(e10, e11);
      }
      const b16x8 E0 = __builtin_bit_cast(b16x8, pk0);
      const b16x8 E1 = __builtin_bit_cast(b16x8, pk1);
#pragma unroll
      for (int g = 0; g < 4; ++g) {
        acc0[g] = __builtin_amdgcn_mfma_f32_16x16x32_bf16(E0, bF[g], acc0[g], 0, 0, 0);
        acc1[g] = __builtin_amdgcn_mfma_f32_16x16x32_bf16(E1, bF[g], acc1[g], 0, 0, 0);
      }
      lacc0 = __builtin_amdgcn_mfma_f32_16x16x32_bf16(E0, ones, lacc0, 0, 0, 0);
      lacc1 = __builtin_amdgcn_mfma_f32_16x16x32_bf16(E1, ones, lacc1, 0, 0, 0);
    }
  }

#pragma unroll
  for (int g = 0; g < 4; ++g)
#pragma unroll
    for (int r = 0; r < 4; ++r) {
      const int col = h * CH + g * 16 + n;
      pacc[((size_t)slice * NN + i0 + q * 4 + r) * C + col] = (_Float16)acc0[g][r];
      pacc[((size_t)slice * NN + i0 + 16 + q * 4 + r) * C + col] = (_Float16)acc1[g][r];
    }
  if (n == 0) {
#pragma unroll
    for (int r = 0; r < 4; ++r) {
      lpart[((size_t)slice * NN + i0 + q * 4 + r) * NH + h] = lacc0[r];
      lpart[((size_t)slice * NN + i0 + 16 + q * 4 + r) * NH + h] = lacc1[r];
    }
  }
}

// ---------------- Kernel 3: combine j-slices, divide
__global__ __launch_bounds__(256) void k_final(
    const _Float16* __restrict__ pacc, const float* __restrict__ lpart,
    float* __restrict__ out) {
  const int i = blockIdx.x;
  const int c = threadIdx.x;
  const int h = c >> 6;
  float l = 0.f, sa = 0.f;
#pragma unroll
  for (int sp = 0; sp < JSPLIT; ++sp) {
    l += lpart[((size_t)sp * NN + i) * NH + h];
    sa += (float)pacc[((size_t)sp * NN + i) * C + c];
  }
  out[(size_t)i * C + c] = sa / l;
}

extern "C" void kernel_launch(void* const* d_in, const int* in_sizes, int n_in,
                              void* d_out, int out_size, void* d_ws, size_t ws_size,
                              hipStream_t stream) {
  const float* nf   = (const float*)d_in[0];
  const int* adj    = (const int*)d_in[1];
  const float* W    = (const float*)d_in[2];
  const float* bias = (const float*)d_in[3];
  const float* av   = (const float*)d_in[4];
  float* out = (float*)d_out;

  char* ws = (char*)d_ws;
  unsigned char* packed  = (unsigned char*)ws;                              // 2 MB
  unsigned short* Xbf    = (unsigned short*)(ws + (2u << 20));              // 2 MB
  unsigned short* WT     = (unsigned short*)(ws + (4u << 20));              // 128 KB
  unsigned short* F      = (unsigned short*)(ws + (4u << 20) + (256u << 10)); // 2 MB
  float2* srcAB = (float2*)(ws + (6u << 20) + (256u << 10));                // 128 KB
  float2* EdT2  = (float2*)(ws + (6u << 20) + (384u << 10));                // 128 KB
  float* lpart  = (float*)(ws + (6u << 20) + (512u << 10));                 // 1 MB
  _Float16* pacc = (_Float16*)(ws + (8u << 20));                            // 32 MB

  k_prep<<<9472, 256, 0, stream>>>(adj, nf, W, packed, Xbf, WT);
  k_feats<<<NN / 16, 256, 0, stream>>>(Xbf, WT, bias, av, F, srcAB, EdT2);
  dim3 g2(JSPLIT, NN / 32);
  k_attn<<<g2, 256, 0, stream>>>(packed, F, srcAB, EdT2, pacc, lpart);
  k_final<<<NN, 256, 0, stream>>>(pacc, lpart, out);
}